// Round 18
// baseline (445.822 us; speedup 1.0000x reference)
//
#include <hip/hip_runtime.h>
#include <cstdint>
#include <cstddef>

typedef unsigned short u16;
typedef __bf16 bf16x8 __attribute__((ext_vector_type(8)));
typedef unsigned short u16x8 __attribute__((ext_vector_type(8)));
typedef float f32x4 __attribute__((ext_vector_type(4)));

#define DIMN 768
#define BNROWS 16384
#define NH 12
#define HD 64
#define HID 3072
#define QKVN 2304

__device__ __forceinline__ u16 f2bf(float f) {
  unsigned u = __builtin_bit_cast(unsigned, f);
  u += 0x7fffu + ((u >> 16) & 1u);
  return (u16)(u >> 16);
}

__device__ __forceinline__ bf16x8 ld8(const u16* p) {
  u16x8 v = *reinterpret_cast<const u16x8*>(p);
  return __builtin_bit_cast(bf16x8, v);
}

__device__ __forceinline__ void gload16(const void* g, void* l) {
  __builtin_amdgcn_global_load_lds(
      (const __attribute__((address_space(1))) unsigned int*)g,
      (__attribute__((address_space(3))) unsigned int*)l, 16, 0, 0);
}

#define MFMA(a, b, c) __builtin_amdgcn_mfma_f32_16x16x32_bf16(a, b, c, 0, 0, 0)

// ------------- fused pre-pass: 4 weight transposes + LN1, one launch ------------------
__global__ __launch_bounds__(256) void pre_k(const float* __restrict__ Wqkv,
                                             const float* __restrict__ Wproj,
                                             const float* __restrict__ W1,
                                             const float* __restrict__ W2,
                                             u16* __restrict__ WqkvT,
                                             u16* __restrict__ WprojT,
                                             u16* __restrict__ W1T,
                                             u16* __restrict__ W2T,
                                             const float* __restrict__ x,
                                             const float* __restrict__ g1,
                                             const float* __restrict__ b1,
                                             u16* __restrict__ h1) {
  __shared__ float tile[32][33];
  int bid = blockIdx.x;
  if (bid < 6912) {
    const float* W;
    u16* Wt;
    int K, N, nx;
    if (bid < 1728) {
      W = Wqkv; Wt = WqkvT; K = DIMN; N = QKVN; nx = 72;
    } else if (bid < 1728 + 576) {
      bid -= 1728; W = Wproj; Wt = WprojT; K = DIMN; N = DIMN; nx = 24;
    } else if (bid < 1728 + 576 + 2304) {
      bid -= 1728 + 576; W = W1; Wt = W1T; K = DIMN; N = HID; nx = 96;
    } else {
      bid -= 1728 + 576 + 2304; W = W2; Wt = W2T; K = HID; N = DIMN; nx = 24;
    }
    const int n0 = (bid % nx) * 32, k0 = (bid / nx) * 32;
    const int tx = threadIdx.x & 31, ty = threadIdx.x >> 5;  // ty 0..7
#pragma unroll
    for (int i = 0; i < 4; i++)
      tile[ty + i * 8][tx] = W[(size_t)(k0 + ty + i * 8) * N + n0 + tx];
    __syncthreads();
#pragma unroll
    for (int i = 0; i < 4; i++)
      Wt[(size_t)(n0 + ty + i * 8) * K + k0 + tx] = f2bf(tile[tx][ty + i * 8]);
  } else {
    const int row = (bid - 6912) * 4 + (threadIdx.x >> 6);
    const int lane = threadIdx.x & 63;
    const float4* xr = (const float4*)(x + (size_t)row * DIMN);
    float4 v[3];
    float s = 0.f, ss = 0.f;
#pragma unroll
    for (int c = 0; c < 3; c++) {
      v[c] = xr[c * 64 + lane];
      s += v[c].x + v[c].y + v[c].z + v[c].w;
      ss += v[c].x * v[c].x + v[c].y * v[c].y + v[c].z * v[c].z + v[c].w * v[c].w;
    }
#pragma unroll
    for (int off = 1; off < 64; off <<= 1) {
      s += __shfl_xor(s, off);
      ss += __shfl_xor(ss, off);
    }
    const float mu = s * (1.f / DIMN);
    const float var = ss * (1.f / DIMN) - mu * mu;
    const float rs = rsqrtf(var + 1e-5f);
    u16* orow = h1 + (size_t)row * DIMN;
#pragma unroll
    for (int c = 0; c < 3; c++) {
      float4 gv = ((const float4*)g1)[c * 64 + lane];
      float4 bv = ((const float4*)b1)[c * 64 + lane];
      ushort4 o;
      o.x = f2bf((v[c].x - mu) * rs * gv.x + bv.x);
      o.y = f2bf((v[c].y - mu) * rs * gv.y + bv.y);
      o.z = f2bf((v[c].z - mu) * rs * gv.z + bv.z);
      o.w = f2bf((v[c].w - mu) * rs * gv.w + bv.w);
      ((ushort4*)orow)[c * 64 + lane] = o;
    }
  }
}

// ---------------- LayerNorm: fp32 row -> bf16 row (one wave per 768-row) ----------------
__global__ __launch_bounds__(256) void ln_k(const float* __restrict__ x,
                                            const float* __restrict__ g,
                                            const float* __restrict__ bta,
                                            u16* __restrict__ outp) {
  const int row = blockIdx.x * 4 + (threadIdx.x >> 6);
  const int lane = threadIdx.x & 63;
  const float4* xr = (const float4*)(x + (size_t)row * DIMN);
  float4 v[3];
  float s = 0.f, ss = 0.f;
#pragma unroll
  for (int c = 0; c < 3; c++) {
    v[c] = xr[c * 64 + lane];
    s += v[c].x + v[c].y + v[c].z + v[c].w;
    ss += v[c].x * v[c].x + v[c].y * v[c].y + v[c].z * v[c].z + v[c].w * v[c].w;
  }
#pragma unroll
  for (int off = 1; off < 64; off <<= 1) {
    s += __shfl_xor(s, off);
    ss += __shfl_xor(ss, off);
  }
  const float mu = s * (1.f / DIMN);
  const float var = ss * (1.f / DIMN) - mu * mu;
  const float rs = rsqrtf(var + 1e-5f);
  u16* orow = outp + (size_t)row * DIMN;
#pragma unroll
  for (int c = 0; c < 3; c++) {
    float4 gv = ((const float4*)g)[c * 64 + lane];
    float4 bv = ((const float4*)bta)[c * 64 + lane];
    ushort4 o;
    o.x = f2bf((v[c].x - mu) * rs * gv.x + bv.x);
    o.y = f2bf((v[c].y - mu) * rs * gv.y + bv.y);
    o.z = f2bf((v[c].z - mu) * rs * gv.z + bv.z);
    o.w = f2bf((v[c].w - mu) * rs * gv.w + bv.w);
    ((ushort4*)orow)[c * 64 + lane] = o;
  }
}

// XCD-aware flat-grid swizzle (T1)
__device__ __forceinline__ void xcd_map(int f, int& bx, int& by) {
  bx = ((f & 7) << 3) | ((f >> 3) & 7);
  by = f >> 6;
}

// ---------------- GEMM 256x256, 8 waves, BK=32, 4-slot ring, 2-phase counted-lgkm -----
// (R9 structure). Used for QKV, FF1. 1D grid + XCD swizzle.
template <int OUT_BF16, int RELU, int RESID>
__global__ __launch_bounds__(512, 2) void gemm256_k(const u16* __restrict__ A,
                                                    const u16* __restrict__ Bt,
                                                    const float* __restrict__ bias,
                                                    const float* __restrict__ resid,
                                                    void* __restrict__ Cout, int N, int K) {
  __shared__ u16 lds[65536];  // 4 slots x (A 16KB + B 16KB) = 128 KiB
  const int tid = threadIdx.x;
  int bx, by;
  xcd_map(blockIdx.x, bx, by);
  const int m0 = bx * 256;
  const int n0 = by * 256;
  const int lane = tid & 63, w = tid >> 6;
  const int wr = w >> 2, wc = w & 3;
  const int lhi = lane >> 4, llo = lane & 15;
  const int rdoff = (lhi ^ ((llo >> 1) & 3)) * 16;
  const int NT = K >> 5;

  const int srow = tid >> 2;
  const int sc8 = ((tid & 3) ^ ((srow >> 1) & 3)) * 8;
  const u16* aS0 = A + (size_t)(m0 + srow) * K + sc8;
  const u16* aS1 = A + (size_t)(m0 + 128 + srow) * K + sc8;
  const u16* bS0 = Bt + (size_t)(n0 + srow) * K + sc8;
  const u16* bS1 = Bt + (size_t)(n0 + 128 + srow) * K + sc8;

  auto slotBase = [&](int t) -> const char* { return (const char*)lds + ((size_t)(t & 3) << 15); };
  auto stageA = [&](int t) {
    char* sb = (char*)lds + ((size_t)(t & 3) << 15);
    gload16(aS0 + t * 32, sb + tid * 16);
    gload16(aS1 + t * 32, sb + 8192 + tid * 16);
  };
  auto stageB = [&](int t) {
    char* sb = (char*)lds + ((size_t)(t & 3) << 15) + 16384;
    gload16(bS0 + t * 32, sb + tid * 16);
    gload16(bS1 + t * 32, sb + 8192 + tid * 16);
  };

  f32x4 acc[8][4] = {};
  bf16x8 a03[2][4], bfr[2][4], a47[4];

  stageB(0); stageA(0);
  stageB(1); stageA(1);
  stageB(2); stageA(2);
  asm volatile("s_waitcnt vmcnt(8)" ::: "memory");
  __builtin_amdgcn_s_barrier();
  {
    const char* sb = slotBase(0);
#pragma unroll
    for (int ni = 0; ni < 4; ni++)
      bfr[0][ni] = ld8((const u16*)(sb + 16384 + (wc * 64 + ni * 16 + llo) * 64 + rdoff));
#pragma unroll
    for (int mi = 0; mi < 4; mi++)
      a03[0][mi] = ld8((const u16*)(sb + (wr * 128 + mi * 16 + llo) * 64 + rdoff));
  }

#define G256_P1(T, CUR)                                                                  \
  {                                                                                      \
    const char* sbp = slotBase(T);                                                       \
    _Pragma("unroll") for (int mi = 0; mi < 4; mi++)                                     \
        a47[mi] = ld8((const u16*)(sbp + (wr * 128 + (4 + mi) * 16 + llo) * 64 + rdoff));\
    if ((T) + 3 < NT) stageB((T) + 3);                                                   \
    if ((T) + 3 < NT) {                                                                  \
      asm volatile("s_waitcnt vmcnt(6)" ::: "memory");                                   \
    } else if ((T) + 2 < NT) {                                                           \
      asm volatile("s_waitcnt vmcnt(4)" ::: "memory");                                   \
    } else if ((T) + 1 < NT) {                                                           \
      asm volatile("s_waitcnt vmcnt(0)" ::: "memory");                                   \
    }                                                                                    \
    __builtin_amdgcn_s_barrier();                                                        \
    asm volatile("s_waitcnt lgkmcnt(4)" ::: "memory");                                   \
    __builtin_amdgcn_sched_barrier(0);                                                   \
    __builtin_amdgcn_s_setprio(1);                                                       \
    _Pragma("unroll") for (int mi = 0; mi < 4; mi++)                                     \
        _Pragma("unroll") for (int ni = 0; ni < 4; ni++)                                 \
            acc[mi][ni] = MFMA(a03[CUR][mi], bfr[CUR][ni], acc[mi][ni]);                 \
    __builtin_amdgcn_s_setprio(0);                                                       \
    __builtin_amdgcn_sched_barrier(0);                                                   \
  }

#define G256_P2(T, CUR, NXT)                                                             \
  {                                                                                      \
    if ((T) + 1 < NT) {                                                                  \
      const char* sbn = slotBase((T) + 1);                                               \
      _Pragma("unroll") for (int ni = 0; ni < 4; ni++)                                   \
          bfr[NXT][ni] =                                                                 \
              ld8((const u16*)(sbn + 16384 + (wc * 64 + ni * 16 + llo) * 64 + rdoff));   \
      _Pragma("unroll") for (int mi = 0; mi < 4; mi++)                                   \
          a03[NXT][mi] = ld8((const u16*)(sbn + (wr * 128 + mi * 16 + llo) * 64 + rdoff));\
    }                                                                                    \
    if ((T) + 3 < NT) stageA((T) + 3);                                                   \
    __builtin_amdgcn_s_barrier();                                                        \
    if ((T) + 1 < NT) {                                                                  \
      asm volatile("s_waitcnt lgkmcnt(8)" ::: "memory");                                 \
    } else {                                                                             \
      asm volatile("s_waitcnt lgkmcnt(0)" ::: "memory");                                 \
    }                                                                                    \
    __builtin_amdgcn_sched_barrier(0);                                                   \
    __builtin_amdgcn_s_setprio(1);                                                       \
    _Pragma("unroll") for (int mi = 0; mi < 4; mi++)                                     \
        _Pragma("unroll") for (int ni = 0; ni < 4; ni++)                                 \
            acc[4 + mi][ni] = MFMA(a47[mi], bfr[CUR][ni], acc[4 + mi][ni]);              \
    __builtin_amdgcn_s_setprio(0);                                                       \
    __builtin_amdgcn_sched_barrier(0);                                                   \
  }

  for (int t = 0; t < NT; t += 2) {
    G256_P1(t, 0)
    G256_P2(t, 0, 1)
    G256_P1(t + 1, 1)
    G256_P2(t + 1, 1, 0)
  }
#undef G256_P1
#undef G256_P2

#pragma unroll
  for (int mi = 0; mi < 8; mi++)
#pragma unroll
    for (int ni = 0; ni < 4; ni++) {
      const int row = m0 + wr * 128 + mi * 16 + lhi * 4;
      const int col = n0 + wc * 64 + ni * 16 + llo;
      const float bsv = bias[col];
#pragma unroll
      for (int rr = 0; rr < 4; rr++) {
        float v = acc[mi][ni][rr] + bsv;
        if (RELU) v = fmaxf(v, 0.0f);
        const size_t idx = (size_t)(row + rr) * N + col;
        if (RESID) v += resid[idx];
        if (OUT_BF16)
          ((u16*)Cout)[idx] = f2bf(v);
        else
          ((float*)Cout)[idx] = v;
      }
    }
}

// ---------------- GEMM 256x128, 4 waves, BK=32, 3-slot ring, 2-phase counted-lgkm -----
// (R9 structure, R9 epilogue). Used for proj, FF2. 1D grid + XCD swizzle.
template <int OUT_BF16, int RELU, int RESID>
__global__ __launch_bounds__(256, 2) void gemmP_k(const u16* __restrict__ A,
                                                  const u16* __restrict__ Bt,
                                                  const float* __restrict__ bias,
                                                  const float* __restrict__ resid,
                                                  void* __restrict__ Cout, int N, int K) {
  __shared__ u16 lds[3 * 12288];
  const int tid = threadIdx.x;
  int bx, by;
  xcd_map(blockIdx.x, bx, by);
  const int m0 = bx * 256;
  const int n0 = by * 128;
  const int lane = tid & 63, w = tid >> 6;
  const int wr = w >> 1, wc = w & 1;
  const int lhi = lane >> 4, llo = lane & 15;
  const int rdoff = (lhi ^ ((llo >> 1) & 3)) * 16;
  const int NT = K >> 5;

  const int crow = tid >> 2;
  const int kc8 = ((tid & 3) ^ ((crow >> 1) & 3)) * 8;
  const u16* aS = A + (size_t)(m0 + crow) * K + kc8;
  const u16* bS = Bt + (size_t)(n0 + crow) * K + kc8;
  const size_t a64 = (size_t)64 * K;

  auto slotBase = [&](int t) -> const char* { return (const char*)lds + (size_t)(t % 3) * 24576; };
  auto stage1 = [&](int t) {
    char* sb = (char*)lds + (size_t)(t % 3) * 24576;
    gload16(aS + t * 32, sb + tid * 16);
    gload16(aS + a64 + t * 32, sb + 4096 + tid * 16);
    gload16(bS + t * 32, sb + 16384 + tid * 16);
  };
  auto stage2 = [&](int t) {
    char* sb = (char*)lds + (size_t)(t % 3) * 24576;
    gload16(aS + 2 * a64 + t * 32, sb + 8192 + tid * 16);
    gload16(aS + 3 * a64 + t * 32, sb + 12288 + tid * 16);
    gload16(bS + a64 + t * 32, sb + 16384 + 4096 + tid * 16);
  };

  f32x4 acc[8][4] = {};
  bf16x8 a03[2][4], bfr[2][4], a47[4];

  stage1(0); stage2(0);
  stage1(1); stage2(1);
  asm volatile("s_waitcnt vmcnt(6)" ::: "memory");
  __builtin_amdgcn_s_barrier();
  {
    const char* sb = slotBase(0);
#pragma unroll
    for (int ni = 0; ni < 4; ni++)
      bfr[0][ni] = ld8((const u16*)(sb + 16384 + (wc * 64 + ni * 16 + llo) * 64 + rdoff));
#pragma unroll
    for (int mi = 0; mi < 4; mi++)
      a03[0][mi] = ld8((const u16*)(sb + (wr * 128 + mi * 16 + llo) * 64 + rdoff));
  }

#define GP_P1(T, CUR)                                                                    \
  {                                                                                      \
    const char* sbp = slotBase(T);                                                       \
    _Pragma("unroll") for (int mi = 0; mi < 4; mi++)                                     \
        a47[mi] = ld8((const u16*)(sbp + (wr * 128 + (4 + mi) * 16 + llo) * 64 + rdoff));\
    if ((T) + 2 < NT) stage1((T) + 2);                                                   \
    if ((T) + 2 < NT) {                                                                  \
      asm volatile("s_waitcnt vmcnt(3)" ::: "memory");                                   \
    } else if ((T) + 1 < NT) {                                                           \
      asm volatile("s_waitcnt vmcnt(0)" ::: "memory");                                   \
    }                                                                                    \
    __builtin_amdgcn_s_barrier();                                                        \
    asm volatile("s_waitcnt lgkmcnt(4)" ::: "memory");                                   \
    __builtin_amdgcn_sched_barrier(0);                                                   \
    __builtin_amdgcn_s_setprio(1);                                                       \
    _Pragma("unroll") for (int mi = 0; mi < 4; mi++)                                     \
        _Pragma("unroll") for (int ni = 0; ni < 4; ni++)                                 \
            acc[mi][ni] = MFMA(a03[CUR][mi], bfr[CUR][ni], acc[mi][ni]);                 \
    __builtin_amdgcn_s_setprio(0);                                                       \
    __builtin_amdgcn_sched_barrier(0);                                                   \
  }

#define GP_P2(T, CUR, NXT)                                                               \
  {                                                                                      \
    if ((T) + 1 < NT) {                                                                  \
      const char* sbn = slotBase((T) + 1);                                               \
      _Pragma("unroll") for (int ni = 0; ni < 4; ni++)                                   \
          bfr[NXT][ni] =                                                                 \
              ld8((const u16*)(sbn + 16384 + (wc * 64 + ni * 16 + llo) * 64 + rdoff));   \
      _Pragma("unroll") for (int mi = 0; mi < 4; mi++)                                   \
          a03[NXT][mi] = ld8((const u16*)(sbn + (wr * 128 + mi * 16 + llo) * 64 + rdoff));\
    }                                                                                    \
    if ((T) + 2 < NT) stage2((T) + 2);                                                   \
    __builtin_amdgcn_s_barrier();                                                        \
    if ((T) + 1 < NT) {                                                                  \
      asm volatile("s_waitcnt lgkmcnt(8)" ::: "memory");                                 \
    } else {                                                                             \
      asm volatile("s_waitcnt lgkmcnt(0)" ::: "memory");                                 \
    }                                                                                    \
    __builtin_amdgcn_sched_barrier(0);                                                   \
    __builtin_amdgcn_s_setprio(1);                                                       \
    _Pragma("unroll") for (int mi = 0; mi < 4; mi++)                                     \
        _Pragma("unroll") for (int ni = 0; ni < 4; ni++)                                 \
            acc[4 + mi][ni] = MFMA(a47[mi], bfr[CUR][ni], acc[4 + mi][ni]);              \
    __builtin_amdgcn_s_setprio(0);                                                       \
    __builtin_amdgcn_sched_barrier(0);                                                   \
  }

  for (int t = 0; t < NT; t += 2) {
    GP_P1(t, 0)
    GP_P2(t, 0, 1)
    GP_P1(t + 1, 1)
    GP_P2(t + 1, 1, 0)
  }
#undef GP_P1
#undef GP_P2

#pragma unroll
  for (int mi = 0; mi < 8; mi++)
#pragma unroll
    for (int ni = 0; ni < 4; ni++) {
      const int row = m0 + wr * 128 + mi * 16 + lhi * 4;
      const int col = n0 + wc * 64 + ni * 16 + llo;
      const float bsv = bias[col];
#pragma unroll
      for (int rr = 0; rr < 4; rr++) {
        float v = acc[mi][ni][rr] + bsv;
        if (RELU) v = fmaxf(v, 0.0f);
        const size_t idx = (size_t)(row + rr) * N + col;
        if (RESID) v += resid[idx];
        if (OUT_BF16)
          ((u16*)Cout)[idx] = f2bf(v);
        else
          ((float*)Cout)[idx] = v;
      }
    }
}

// ---------------- fused attention: 40KB LDS -> 4 blocks/CU, ks-split Ps ---------------
// LDS: Ks 2x8K + Vt 2x8K + Ps 8K = 40 KB (exactly 4 blocks/CU at 160 KB).
// Ps[4][32q][32kv] per ks-half; swizzle: element (q, kv_local) stored at
// kv_local ^ ((q&3)*8) (bijective in 0..31; uint2 write stays 4-aligned; b128 read
// contiguous since XOR hits bits 3..4 only). Writes/reads use the same q&3 involution.
// Ps is wave-private: per-wave DS FIFO orders ks0-read < ks1-write (WAR) and tile order.
// Sync ledger per tile t unchanged from R11 (2-slot Ks/Vt, counted vmcnt, 2 barriers).
__device__ __forceinline__ bf16x8 ldscale8(const u16* p, float c) {
  u16x8 v = *reinterpret_cast<const u16x8*>(p);
  bf16x8 r;
#pragma unroll
  for (int j = 0; j < 8; j++) {
    float f = __builtin_bit_cast(float, (unsigned)v[j] << 16) * c;
    r[j] = (__bf16)f;
  }
  return r;
}

__device__ __forceinline__ unsigned pack_bf2(float a, float b) {
  unsigned ua = (unsigned)__builtin_bit_cast(u16, (__bf16)a);
  unsigned ub = (unsigned)__builtin_bit_cast(u16, (__bf16)b);
  return ua | (ub << 16);
}

__global__ __launch_bounds__(256, 4) void attn_k(const u16* __restrict__ qkv,
                                                 u16* __restrict__ outp) {
  __shared__ u16 Ks[2][64 * 64];  // K[kv][d], 16B-unit u holds G-unit u^(kv&7)
  __shared__ u16 Vt[2][64 * 64];  // V^T[d][kv], kv swizzled by ((d&7)*8)
  __shared__ u16 Ps[4][32 * 32];  // per-wave P[q][kv_local], kv^((q&3)*8)

  const int tid = threadIdx.x;
  const int f = blockIdx.x;                  // 0..1535
  const int bh = (f & 7) | ((f >> 6) << 3);  // all 8 q-tiles of one bh on one XCD
  const int qt = (f >> 3) & 7;
  const int b = bh / NH, h = bh - b * NH;
  const int lane = tid & 63, w = tid >> 6;
  const int lhi = lane >> 4, llo = lane & 15;
  const size_t rowb = (size_t)b * 1024;
  const int wq0 = qt * 128 + w * 32;
  const float SC = 0.052059750f;  // 768^-0.5 * log2(e)

  bf16x8 qb[2][2];
#pragma unroll
  for (int mi = 0; mi < 2; mi++) {
    const u16* qrow = qkv + (rowb + wq0 + mi * 16 + llo) * QKVN + h * HD;
    qb[mi][0] = ldscale8(qrow + lhi * 8, SC);
    qb[mi][1] = ldscale8(qrow + 32 + lhi * 8, SC);
  }

  bf16x8 ones;
#pragma unroll
  for (int j = 0; j < 8; j++) ones[j] = (__bf16)1.0f;

  const u16* kbase = qkv + rowb * QKVN + DIMN + h * HD;
  const u16* vbase = qkv + rowb * QKVN + 2 * DIMN + h * HD;
  const int sw = (llo & 7) * 8;   // Vt swizzle (64-wide rows)
  const int psw = (llo & 3) * 8;  // Ps swizzle (32-wide rows)
  const int rsw = llo & 7;

  const int srow = tid >> 3, su = tid & 7;
  const u16* ksrc = kbase + (size_t)srow * QKVN + (su ^ (srow & 7)) * 8;
  auto stageK = [&](int kt, int slot) {
    const u16* s0 = ksrc + (size_t)kt * 64 * QKVN;
    gload16(s0, (char*)&Ks[slot][0] + tid * 16);
    gload16(s0 + (size_t)32 * QKVN, (char*)&Ks[slot][0] + 4096 + tid * 16);
  };

  const int vp = (lane & 31) * 2;
  const int dc = w * 8 + (lane >> 5) * 32;
  auto loadV = [&](int kt, u16x8& a, u16x8& c) {
    const u16* vr = vbase + (size_t)(kt * 64 + vp) * QKVN + dc;
    a = *reinterpret_cast<const u16x8*>(vr);
    c = *reinterpret_cast<const u16x8*>(vr + QKVN);
  };
  auto writeV = [&](int buf, u16x8 a, u16x8 c) {
#pragma unroll
    for (int j = 0; j < 8; j++) {
      unsigned val = (unsigned)a[j] | ((unsigned)c[j] << 16);
      *reinterpret_cast<unsigned*>(&Vt[buf][(dc + j) * 64 + (vp ^ (j * 8))]) = val;
    }
  };

  u16x8 v0, v1, nv0, nv1;

  stageK(0, 0);
  loadV(0, v0, v1);
  stageK(1, 1);
  asm volatile("s_waitcnt vmcnt(2)" ::: "memory");
  writeV(0, v0, v1);
  asm volatile("s_waitcnt lgkmcnt(0)" ::: "memory");
  __builtin_amdgcn_s_barrier();
  __builtin_amdgcn_sched_barrier(0);

  f32x4 oacc[2][4] = {};
  f32x4 racc[2] = {};

  for (int t = 0; t < 16; t++) {
    if (t < 15) loadV(t + 1, nv0, nv1);

    const u16* kB = &Ks[t & 1][0];
    f32x4 sacc[4][2] = {};
#pragma unroll
    for (int ks = 0; ks < 2; ks++)
#pragma unroll
      for (int ni = 0; ni < 4; ni++) {
        bf16x8 kf = ld8(&kB[(ni * 16 + llo) * 64 + (((ks * 4 + lhi) ^ rsw) * 8)]);
#pragma unroll
        for (int mi = 0; mi < 2; mi++) sacc[ni][mi] = MFMA(kf, qb[mi][ks], sacc[ni][mi]);
      }

    asm volatile("s_waitcnt lgkmcnt(0)" ::: "memory");
    __builtin_amdgcn_s_barrier();  // all waves done reading Ks[t&1]
    __builtin_amdgcn_sched_barrier(0);
    if (t + 2 < 16) stageK(t + 2, t & 1);

    // ---- per ks-half: P = 2^(S') -> Ps (32-wide) -> PV + rowsum ----
#pragma unroll
    for (int ks = 0; ks < 2; ks++) {
#pragma unroll
      for (int mi = 0; mi < 2; mi++)
#pragma unroll
        for (int nl = 0; nl < 2; nl++) {
          const int ni = ks * 2 + nl;
          float p0 = __builtin_amdgcn_exp2f(sacc[ni][mi][0]);
          float p1 = __builtin_amdgcn_exp2f(sacc[ni][mi][1]);
          float p2 = __builtin_amdgcn_exp2f(sacc[ni][mi][2]);
          float p3 = __builtin_amdgcn_exp2f(sacc[ni][mi][3]);
          u16* pp = &Ps[w][(mi * 16 + llo) * 32 + ((nl * 16 + lhi * 4) ^ psw)];
          uint2 pw;
          pw.x = pack_bf2(p0, p1);
          pw.y = pack_bf2(p2, p3);
          *reinterpret_cast<uint2*>(pp) = pw;  // ds_write_b64
        }
      // Ps RAW: within-wave DS program order
      const int koff = ks * 32 + lhi * 8;
      const int poff = (lhi * 8) ^ psw;
      bf16x8 pa0 = ld8(&Ps[w][llo * 32 + poff]);
      bf16x8 pa1 = ld8(&Ps[w][(16 + llo) * 32 + poff]);
#pragma unroll
      for (int ni = 0; ni < 4; ni++) {
        bf16x8 vb = ld8(&Vt[t & 1][(ni * 16 + llo) * 64 + (koff ^ sw)]);
        oacc[0][ni] = MFMA(pa0, vb, oacc[0][ni]);
        oacc[1][ni] = MFMA(pa1, vb, oacc[1][ni]);
      }
      racc[0] = MFMA(pa0, ones, racc[0]);
      racc[1] = MFMA(pa1, ones, racc[1]);
    }

    if (t < 15) {
      if (t + 2 < 16) {
        asm volatile("s_waitcnt vmcnt(2)" ::: "memory");
      } else {
        asm volatile("s_waitcnt vmcnt(0)" ::: "memory");
      }
      writeV((t + 1) & 1, nv0, nv1);
      v0 = nv0; v1 = nv1;
      asm volatile("s_waitcnt lgkmcnt(0)" ::: "memory");
      __builtin_amdgcn_s_barrier();
      __builtin_amdgcn_sched_barrier(0);
    }
  }

#pragma unroll
  for (int mi = 0; mi < 2; mi++)
#pragma unroll
    for (int ni = 0; ni < 4; ni++)
#pragma unroll
      for (int r = 0; r < 4; r++) {
        const size_t row = rowb + wq0 + mi * 16 + lhi * 4 + r;
        outp[row * DIMN + h * HD + ni * 16 + llo] = f2bf(oacc[mi][ni][r] / racc[mi][r]);
      }
}

extern "C" void kernel_launch(void* const* d_in, const int* in_sizes, int n_in,
                              void* d_out, int out_size, void* d_ws, size_t ws_size,
                              hipStream_t stream) {
  const float* x = (const float*)d_in[0];
  const float* Wqkv = (const float*)d_in[1];
  const float* bqkv = (const float*)d_in[2];
  const float* Wproj = (const float*)d_in[3];
  const float* bproj = (const float*)d_in[4];
  const float* g1 = (const float*)d_in[5];
  const float* b1 = (const float*)d_in[6];
  const float* g2 = (const float*)d_in[7];
  const float* b2 = (const float*)d_in[8];
  const float* W1 = (const float*)d_in[9];
  const float* bf1 = (const float*)d_in[10];
  const float* W2 = (const float*)d_in[11];
  const float* bf2 = (const float*)d_in[12];
  float* outp = (float*)d_out;

  char* p = (char*)d_ws;
  u16* WqkvT = (u16*)p; p += (size_t)QKVN * DIMN * 2;
  u16* WprojT = (u16*)p; p += (size_t)DIMN * DIMN * 2;
  u16* W1T = (u16*)p; p += (size_t)HID * DIMN * 2;
  u16* W2T = (u16*)p; p += (size_t)DIMN * HID * 2;
  u16* bufX = (u16*)p; p += (size_t)BNROWS * DIMN * 2;  // h1 / attn_out / h2
  u16* big = (u16*)p; p += (size_t)BNROWS * HID * 2;    // qkv then ff1

  // fused pre-pass: 4 weight transposes + LN1 (one launch, 11008 blocks)
  pre_k<<<11008, 256, 0, stream>>>(Wqkv, Wproj, W1, W2, WqkvT, WprojT, W1T, W2T,
                                   x, g1, b1, bufX);

  // QKV GEMM -> big (bf16): 576 blocks, XCD-swizzled flat grid
  gemm256_k<1, 0, 0><<<64 * (QKVN / 256), 512, 0, stream>>>(bufX, WqkvT, bqkv, nullptr,
                                                            big, QKVN, DIMN);
  attn_k<<<1536, 256, 0, stream>>>(big, bufX);
  // proj GEMM + residual(x) -> d_out (fp32): 384 blocks
  gemmP_k<0, 0, 1><<<64 * (DIMN / 128), 256, 0, stream>>>(bufX, WprojT, bproj, x, outp,
                                                          DIMN, DIMN);
  ln_k<<<BNROWS / 4, 256, 0, stream>>>(outp, g2, b2, bufX);
  // FF1 (relu) -> big (bf16): 768 blocks
  gemm256_k<1, 1, 0><<<64 * (HID / 256), 512, 0, stream>>>(bufX, W1T, bf1, nullptr, big,
                                                           HID, DIMN);
  // FF2 + residual(d_out) -> d_out (fp32, in place): 384 blocks
  gemmP_k<0, 0, 1><<<64 * (DIMN / 128), 256, 0, stream>>>(big, W2T, bf2, outp, outp,
                                                          DIMN, HID);
}

// Round 19
// 413.748 us; speedup vs baseline: 1.0775x; 1.0775x over previous
//
#include <hip/hip_runtime.h>
#include <cstdint>
#include <cstddef>

typedef unsigned short u16;
typedef __bf16 bf16x8 __attribute__((ext_vector_type(8)));
typedef unsigned short u16x8 __attribute__((ext_vector_type(8)));
typedef float f32x4 __attribute__((ext_vector_type(4)));

#define DIMN 768
#define BNROWS 16384
#define NH 12
#define HD 64
#define HID 3072
#define QKVN 2304

__device__ __forceinline__ u16 f2bf(float f) {
  unsigned u = __builtin_bit_cast(unsigned, f);
  u += 0x7fffu + ((u >> 16) & 1u);
  return (u16)(u >> 16);
}

__device__ __forceinline__ bf16x8 ld8(const u16* p) {
  u16x8 v = *reinterpret_cast<const u16x8*>(p);
  return __builtin_bit_cast(bf16x8, v);
}

__device__ __forceinline__ void gload16(const void* g, void* l) {
  __builtin_amdgcn_global_load_lds(
      (const __attribute__((address_space(1))) unsigned int*)g,
      (__attribute__((address_space(3))) unsigned int*)l, 16, 0, 0);
}

#define MFMA(a, b, c) __builtin_amdgcn_mfma_f32_16x16x32_bf16(a, b, c, 0, 0, 0)

// ------------- fused pre-pass: 4 weight transposes + LN1, one launch ------------------
__global__ __launch_bounds__(256) void pre_k(const float* __restrict__ Wqkv,
                                             const float* __restrict__ Wproj,
                                             const float* __restrict__ W1,
                                             const float* __restrict__ W2,
                                             u16* __restrict__ WqkvT,
                                             u16* __restrict__ WprojT,
                                             u16* __restrict__ W1T,
                                             u16* __restrict__ W2T,
                                             const float* __restrict__ x,
                                             const float* __restrict__ g1,
                                             const float* __restrict__ b1,
                                             u16* __restrict__ h1) {
  __shared__ float tile[32][33];
  int bid = blockIdx.x;
  if (bid < 6912) {
    const float* W;
    u16* Wt;
    int K, N, nx;
    if (bid < 1728) {
      W = Wqkv; Wt = WqkvT; K = DIMN; N = QKVN; nx = 72;
    } else if (bid < 1728 + 576) {
      bid -= 1728; W = Wproj; Wt = WprojT; K = DIMN; N = DIMN; nx = 24;
    } else if (bid < 1728 + 576 + 2304) {
      bid -= 1728 + 576; W = W1; Wt = W1T; K = DIMN; N = HID; nx = 96;
    } else {
      bid -= 1728 + 576 + 2304; W = W2; Wt = W2T; K = HID; N = DIMN; nx = 24;
    }
    const int n0 = (bid % nx) * 32, k0 = (bid / nx) * 32;
    const int tx = threadIdx.x & 31, ty = threadIdx.x >> 5;  // ty 0..7
#pragma unroll
    for (int i = 0; i < 4; i++)
      tile[ty + i * 8][tx] = W[(size_t)(k0 + ty + i * 8) * N + n0 + tx];
    __syncthreads();
#pragma unroll
    for (int i = 0; i < 4; i++)
      Wt[(size_t)(n0 + ty + i * 8) * K + k0 + tx] = f2bf(tile[tx][ty + i * 8]);
  } else {
    const int row = (bid - 6912) * 4 + (threadIdx.x >> 6);
    const int lane = threadIdx.x & 63;
    const float4* xr = (const float4*)(x + (size_t)row * DIMN);
    float4 v[3];
    float s = 0.f, ss = 0.f;
#pragma unroll
    for (int c = 0; c < 3; c++) {
      v[c] = xr[c * 64 + lane];
      s += v[c].x + v[c].y + v[c].z + v[c].w;
      ss += v[c].x * v[c].x + v[c].y * v[c].y + v[c].z * v[c].z + v[c].w * v[c].w;
    }
#pragma unroll
    for (int off = 1; off < 64; off <<= 1) {
      s += __shfl_xor(s, off);
      ss += __shfl_xor(ss, off);
    }
    const float mu = s * (1.f / DIMN);
    const float var = ss * (1.f / DIMN) - mu * mu;
    const float rs = rsqrtf(var + 1e-5f);
    u16* orow = h1 + (size_t)row * DIMN;
#pragma unroll
    for (int c = 0; c < 3; c++) {
      float4 gv = ((const float4*)g1)[c * 64 + lane];
      float4 bv = ((const float4*)b1)[c * 64 + lane];
      ushort4 o;
      o.x = f2bf((v[c].x - mu) * rs * gv.x + bv.x);
      o.y = f2bf((v[c].y - mu) * rs * gv.y + bv.y);
      o.z = f2bf((v[c].z - mu) * rs * gv.z + bv.z);
      o.w = f2bf((v[c].w - mu) * rs * gv.w + bv.w);
      ((ushort4*)orow)[c * 64 + lane] = o;
    }
  }
}

// ---------------- LayerNorm: fp32 row -> bf16 row (one wave per 768-row) ----------------
__global__ __launch_bounds__(256) void ln_k(const float* __restrict__ x,
                                            const float* __restrict__ g,
                                            const float* __restrict__ bta,
                                            u16* __restrict__ outp) {
  const int row = blockIdx.x * 4 + (threadIdx.x >> 6);
  const int lane = threadIdx.x & 63;
  const float4* xr = (const float4*)(x + (size_t)row * DIMN);
  float4 v[3];
  float s = 0.f, ss = 0.f;
#pragma unroll
  for (int c = 0; c < 3; c++) {
    v[c] = xr[c * 64 + lane];
    s += v[c].x + v[c].y + v[c].z + v[c].w;
    ss += v[c].x * v[c].x + v[c].y * v[c].y + v[c].z * v[c].z + v[c].w * v[c].w;
  }
#pragma unroll
  for (int off = 1; off < 64; off <<= 1) {
    s += __shfl_xor(s, off);
    ss += __shfl_xor(ss, off);
  }
  const float mu = s * (1.f / DIMN);
  const float var = ss * (1.f / DIMN) - mu * mu;
  const float rs = rsqrtf(var + 1e-5f);
  u16* orow = outp + (size_t)row * DIMN;
#pragma unroll
  for (int c = 0; c < 3; c++) {
    float4 gv = ((const float4*)g)[c * 64 + lane];
    float4 bv = ((const float4*)bta)[c * 64 + lane];
    ushort4 o;
    o.x = f2bf((v[c].x - mu) * rs * gv.x + bv.x);
    o.y = f2bf((v[c].y - mu) * rs * gv.y + bv.y);
    o.z = f2bf((v[c].z - mu) * rs * gv.z + bv.z);
    o.w = f2bf((v[c].w - mu) * rs * gv.w + bv.w);
    ((ushort4*)orow)[c * 64 + lane] = o;
  }
}

// XCD-aware flat-grid swizzle (T1)
__device__ __forceinline__ void xcd_map(int f, int& bx, int& by) {
  bx = ((f & 7) << 3) | ((f >> 3) & 7);
  by = f >> 6;
}

// ---------------- GEMM 256x256, 8 waves, BK=32, 4-slot ring, 2-phase counted-lgkm -----
// (R9 structure). Used for QKV, FF1. 1D grid + XCD swizzle.
template <int OUT_BF16, int RELU, int RESID>
__global__ __launch_bounds__(512, 2) void gemm256_k(const u16* __restrict__ A,
                                                    const u16* __restrict__ Bt,
                                                    const float* __restrict__ bias,
                                                    const float* __restrict__ resid,
                                                    void* __restrict__ Cout, int N, int K) {
  __shared__ u16 lds[65536];  // 4 slots x (A 16KB + B 16KB) = 128 KiB
  const int tid = threadIdx.x;
  int bx, by;
  xcd_map(blockIdx.x, bx, by);
  const int m0 = bx * 256;
  const int n0 = by * 256;
  const int lane = tid & 63, w = tid >> 6;
  const int wr = w >> 2, wc = w & 3;
  const int lhi = lane >> 4, llo = lane & 15;
  const int rdoff = (lhi ^ ((llo >> 1) & 3)) * 16;
  const int NT = K >> 5;

  const int srow = tid >> 2;
  const int sc8 = ((tid & 3) ^ ((srow >> 1) & 3)) * 8;
  const u16* aS0 = A + (size_t)(m0 + srow) * K + sc8;
  const u16* aS1 = A + (size_t)(m0 + 128 + srow) * K + sc8;
  const u16* bS0 = Bt + (size_t)(n0 + srow) * K + sc8;
  const u16* bS1 = Bt + (size_t)(n0 + 128 + srow) * K + sc8;

  auto slotBase = [&](int t) -> const char* { return (const char*)lds + ((size_t)(t & 3) << 15); };
  auto stageA = [&](int t) {
    char* sb = (char*)lds + ((size_t)(t & 3) << 15);
    gload16(aS0 + t * 32, sb + tid * 16);
    gload16(aS1 + t * 32, sb + 8192 + tid * 16);
  };
  auto stageB = [&](int t) {
    char* sb = (char*)lds + ((size_t)(t & 3) << 15) + 16384;
    gload16(bS0 + t * 32, sb + tid * 16);
    gload16(bS1 + t * 32, sb + 8192 + tid * 16);
  };

  f32x4 acc[8][4] = {};
  bf16x8 a03[2][4], bfr[2][4], a47[4];

  stageB(0); stageA(0);
  stageB(1); stageA(1);
  stageB(2); stageA(2);
  asm volatile("s_waitcnt vmcnt(8)" ::: "memory");
  __builtin_amdgcn_s_barrier();
  {
    const char* sb = slotBase(0);
#pragma unroll
    for (int ni = 0; ni < 4; ni++)
      bfr[0][ni] = ld8((const u16*)(sb + 16384 + (wc * 64 + ni * 16 + llo) * 64 + rdoff));
#pragma unroll
    for (int mi = 0; mi < 4; mi++)
      a03[0][mi] = ld8((const u16*)(sb + (wr * 128 + mi * 16 + llo) * 64 + rdoff));
  }

#define G256_P1(T, CUR)                                                                  \
  {                                                                                      \
    const char* sbp = slotBase(T);                                                       \
    _Pragma("unroll") for (int mi = 0; mi < 4; mi++)                                     \
        a47[mi] = ld8((const u16*)(sbp + (wr * 128 + (4 + mi) * 16 + llo) * 64 + rdoff));\
    if ((T) + 3 < NT) stageB((T) + 3);                                                   \
    if ((T) + 3 < NT) {                                                                  \
      asm volatile("s_waitcnt vmcnt(6)" ::: "memory");                                   \
    } else if ((T) + 2 < NT) {                                                           \
      asm volatile("s_waitcnt vmcnt(4)" ::: "memory");                                   \
    } else if ((T) + 1 < NT) {                                                           \
      asm volatile("s_waitcnt vmcnt(0)" ::: "memory");                                   \
    }                                                                                    \
    __builtin_amdgcn_s_barrier();                                                        \
    asm volatile("s_waitcnt lgkmcnt(4)" ::: "memory");                                   \
    __builtin_amdgcn_sched_barrier(0);                                                   \
    __builtin_amdgcn_s_setprio(1);                                                       \
    _Pragma("unroll") for (int mi = 0; mi < 4; mi++)                                     \
        _Pragma("unroll") for (int ni = 0; ni < 4; ni++)                                 \
            acc[mi][ni] = MFMA(a03[CUR][mi], bfr[CUR][ni], acc[mi][ni]);                 \
    __builtin_amdgcn_s_setprio(0);                                                       \
    __builtin_amdgcn_sched_barrier(0);                                                   \
  }

#define G256_P2(T, CUR, NXT)                                                             \
  {                                                                                      \
    if ((T) + 1 < NT) {                                                                  \
      const char* sbn = slotBase((T) + 1);                                               \
      _Pragma("unroll") for (int ni = 0; ni < 4; ni++)                                   \
          bfr[NXT][ni] =                                                                 \
              ld8((const u16*)(sbn + 16384 + (wc * 64 + ni * 16 + llo) * 64 + rdoff));   \
      _Pragma("unroll") for (int mi = 0; mi < 4; mi++)                                   \
          a03[NXT][mi] = ld8((const u16*)(sbn + (wr * 128 + mi * 16 + llo) * 64 + rdoff));\
    }                                                                                    \
    if ((T) + 3 < NT) stageA((T) + 3);                                                   \
    __builtin_amdgcn_s_barrier();                                                        \
    if ((T) + 1 < NT) {                                                                  \
      asm volatile("s_waitcnt lgkmcnt(8)" ::: "memory");                                 \
    } else {                                                                             \
      asm volatile("s_waitcnt lgkmcnt(0)" ::: "memory");                                 \
    }                                                                                    \
    __builtin_amdgcn_sched_barrier(0);                                                   \
    __builtin_amdgcn_s_setprio(1);                                                       \
    _Pragma("unroll") for (int mi = 0; mi < 4; mi++)                                     \
        _Pragma("unroll") for (int ni = 0; ni < 4; ni++)                                 \
            acc[4 + mi][ni] = MFMA(a47[mi], bfr[CUR][ni], acc[4 + mi][ni]);              \
    __builtin_amdgcn_s_setprio(0);                                                       \
    __builtin_amdgcn_sched_barrier(0);                                                   \
  }

  for (int t = 0; t < NT; t += 2) {
    G256_P1(t, 0)
    G256_P2(t, 0, 1)
    G256_P1(t + 1, 1)
    G256_P2(t + 1, 1, 0)
  }
#undef G256_P1
#undef G256_P2

#pragma unroll
  for (int mi = 0; mi < 8; mi++)
#pragma unroll
    for (int ni = 0; ni < 4; ni++) {
      const int row = m0 + wr * 128 + mi * 16 + lhi * 4;
      const int col = n0 + wc * 64 + ni * 16 + llo;
      const float bsv = bias[col];
#pragma unroll
      for (int rr = 0; rr < 4; rr++) {
        float v = acc[mi][ni][rr] + bsv;
        if (RELU) v = fmaxf(v, 0.0f);
        const size_t idx = (size_t)(row + rr) * N + col;
        if (RESID) v += resid[idx];
        if (OUT_BF16)
          ((u16*)Cout)[idx] = f2bf(v);
        else
          ((float*)Cout)[idx] = v;
      }
    }
}

// ---------------- GEMM 256x128, 4 waves, BK=32, 3-slot ring, 2-phase counted-lgkm -----
// (R9 structure, R9 epilogue). Used for proj, FF2. 1D grid + XCD swizzle.
template <int OUT_BF16, int RELU, int RESID>
__global__ __launch_bounds__(256, 2) void gemmP_k(const u16* __restrict__ A,
                                                  const u16* __restrict__ Bt,
                                                  const float* __restrict__ bias,
                                                  const float* __restrict__ resid,
                                                  void* __restrict__ Cout, int N, int K) {
  __shared__ u16 lds[3 * 12288];
  const int tid = threadIdx.x;
  int bx, by;
  xcd_map(blockIdx.x, bx, by);
  const int m0 = bx * 256;
  const int n0 = by * 128;
  const int lane = tid & 63, w = tid >> 6;
  const int wr = w >> 1, wc = w & 1;
  const int lhi = lane >> 4, llo = lane & 15;
  const int rdoff = (lhi ^ ((llo >> 1) & 3)) * 16;
  const int NT = K >> 5;

  const int crow = tid >> 2;
  const int kc8 = ((tid & 3) ^ ((crow >> 1) & 3)) * 8;
  const u16* aS = A + (size_t)(m0 + crow) * K + kc8;
  const u16* bS = Bt + (size_t)(n0 + crow) * K + kc8;
  const size_t a64 = (size_t)64 * K;

  auto slotBase = [&](int t) -> const char* { return (const char*)lds + (size_t)(t % 3) * 24576; };
  auto stage1 = [&](int t) {
    char* sb = (char*)lds + (size_t)(t % 3) * 24576;
    gload16(aS + t * 32, sb + tid * 16);
    gload16(aS + a64 + t * 32, sb + 4096 + tid * 16);
    gload16(bS + t * 32, sb + 16384 + tid * 16);
  };
  auto stage2 = [&](int t) {
    char* sb = (char*)lds + (size_t)(t % 3) * 24576;
    gload16(aS + 2 * a64 + t * 32, sb + 8192 + tid * 16);
    gload16(aS + 3 * a64 + t * 32, sb + 12288 + tid * 16);
    gload16(bS + a64 + t * 32, sb + 16384 + 4096 + tid * 16);
  };

  f32x4 acc[8][4] = {};
  bf16x8 a03[2][4], bfr[2][4], a47[4];

  stage1(0); stage2(0);
  stage1(1); stage2(1);
  asm volatile("s_waitcnt vmcnt(6)" ::: "memory");
  __builtin_amdgcn_s_barrier();
  {
    const char* sb = slotBase(0);
#pragma unroll
    for (int ni = 0; ni < 4; ni++)
      bfr[0][ni] = ld8((const u16*)(sb + 16384 + (wc * 64 + ni * 16 + llo) * 64 + rdoff));
#pragma unroll
    for (int mi = 0; mi < 4; mi++)
      a03[0][mi] = ld8((const u16*)(sb + (wr * 128 + mi * 16 + llo) * 64 + rdoff));
  }

#define GP_P1(T, CUR)                                                                    \
  {                                                                                      \
    const char* sbp = slotBase(T);                                                       \
    _Pragma("unroll") for (int mi = 0; mi < 4; mi++)                                     \
        a47[mi] = ld8((const u16*)(sbp + (wr * 128 + (4 + mi) * 16 + llo) * 64 + rdoff));\
    if ((T) + 2 < NT) stage1((T) + 2);                                                   \
    if ((T) + 2 < NT) {                                                                  \
      asm volatile("s_waitcnt vmcnt(3)" ::: "memory");                                   \
    } else if ((T) + 1 < NT) {                                                           \
      asm volatile("s_waitcnt vmcnt(0)" ::: "memory");                                   \
    }                                                                                    \
    __builtin_amdgcn_s_barrier();                                                        \
    asm volatile("s_waitcnt lgkmcnt(4)" ::: "memory");                                   \
    __builtin_amdgcn_sched_barrier(0);                                                   \
    __builtin_amdgcn_s_setprio(1);                                                       \
    _Pragma("unroll") for (int mi = 0; mi < 4; mi++)                                     \
        _Pragma("unroll") for (int ni = 0; ni < 4; ni++)                                 \
            acc[mi][ni] = MFMA(a03[CUR][mi], bfr[CUR][ni], acc[mi][ni]);                 \
    __builtin_amdgcn_s_setprio(0);                                                       \
    __builtin_amdgcn_sched_barrier(0);                                                   \
  }

#define GP_P2(T, CUR, NXT)                                                               \
  {                                                                                      \
    if ((T) + 1 < NT) {                                                                  \
      const char* sbn = slotBase((T) + 1);                                               \
      _Pragma("unroll") for (int ni = 0; ni < 4; ni++)                                   \
          bfr[NXT][ni] =                                                                 \
              ld8((const u16*)(sbn + 16384 + (wc * 64 + ni * 16 + llo) * 64 + rdoff));   \
      _Pragma("unroll") for (int mi = 0; mi < 4; mi++)                                   \
          a03[NXT][mi] = ld8((const u16*)(sbn + (wr * 128 + mi * 16 + llo) * 64 + rdoff));\
    }                                                                                    \
    if ((T) + 2 < NT) stage2((T) + 2);                                                   \
    __builtin_amdgcn_s_barrier();                                                        \
    if ((T) + 1 < NT) {                                                                  \
      asm volatile("s_waitcnt lgkmcnt(8)" ::: "memory");                                 \
    } else {                                                                             \
      asm volatile("s_waitcnt lgkmcnt(0)" ::: "memory");                                 \
    }                                                                                    \
    __builtin_amdgcn_sched_barrier(0);                                                   \
    __builtin_amdgcn_s_setprio(1);                                                       \
    _Pragma("unroll") for (int mi = 0; mi < 4; mi++)                                     \
        _Pragma("unroll") for (int ni = 0; ni < 4; ni++)                                 \
            acc[4 + mi][ni] = MFMA(a47[mi], bfr[CUR][ni], acc[4 + mi][ni]);              \
    __builtin_amdgcn_s_setprio(0);                                                       \
    __builtin_amdgcn_sched_barrier(0);                                                   \
  }

  for (int t = 0; t < NT; t += 2) {
    GP_P1(t, 0)
    GP_P2(t, 0, 1)
    GP_P1(t + 1, 1)
    GP_P2(t + 1, 1, 0)
  }
#undef GP_P1
#undef GP_P2

#pragma unroll
  for (int mi = 0; mi < 8; mi++)
#pragma unroll
    for (int ni = 0; ni < 4; ni++) {
      const int row = m0 + wr * 128 + mi * 16 + lhi * 4;
      const int col = n0 + wc * 64 + ni * 16 + llo;
      const float bsv = bias[col];
#pragma unroll
      for (int rr = 0; rr < 4; rr++) {
        float v = acc[mi][ni][rr] + bsv;
        if (RELU) v = fmaxf(v, 0.0f);
        const size_t idx = (size_t)(row + rr) * N + col;
        if (RESID) v += resid[idx];
        if (OUT_BF16)
          ((u16*)Cout)[idx] = f2bf(v);
        else
          ((float*)Cout)[idx] = v;
      }
    }
}

// ---------------- fused attention (R16-verified: 48KB LDS, 3 blk/CU, ones-MFMA) -------
__device__ __forceinline__ bf16x8 ldscale8(const u16* p, float c) {
  u16x8 v = *reinterpret_cast<const u16x8*>(p);
  bf16x8 r;
#pragma unroll
  for (int j = 0; j < 8; j++) {
    float f = __builtin_bit_cast(float, (unsigned)v[j] << 16) * c;
    r[j] = (__bf16)f;
  }
  return r;
}

__device__ __forceinline__ unsigned pack_bf2(float a, float b) {
  unsigned ua = (unsigned)__builtin_bit_cast(u16, (__bf16)a);
  unsigned ub = (unsigned)__builtin_bit_cast(u16, (__bf16)b);
  return ua | (ub << 16);
}

__global__ __launch_bounds__(256, 3) void attn_k(const u16* __restrict__ qkv,
                                                 u16* __restrict__ outp) {
  __shared__ u16 Ks[2][64 * 64];  // K[kv][d], 16B-unit u holds G-unit u^(kv&7)
  __shared__ u16 Vt[2][64 * 64];  // V^T[d][kv], kv swizzled by ((d&7)*8)
  __shared__ u16 Ps[4][32 * 64];  // per-wave P[q][kv], kv swizzled by ((q&7)*8)

  const int tid = threadIdx.x;
  const int f = blockIdx.x;                  // 0..1535
  const int bh = (f & 7) | ((f >> 6) << 3);  // all 8 q-tiles of one bh on one XCD
  const int qt = (f >> 3) & 7;
  const int b = bh / NH, h = bh - b * NH;
  const int lane = tid & 63, w = tid >> 6;
  const int lhi = lane >> 4, llo = lane & 15;
  const size_t rowb = (size_t)b * 1024;
  const int wq0 = qt * 128 + w * 32;
  const float SC = 0.052059750f;  // 768^-0.5 * log2(e)

  bf16x8 qb[2][2];
#pragma unroll
  for (int mi = 0; mi < 2; mi++) {
    const u16* qrow = qkv + (rowb + wq0 + mi * 16 + llo) * QKVN + h * HD;
    qb[mi][0] = ldscale8(qrow + lhi * 8, SC);
    qb[mi][1] = ldscale8(qrow + 32 + lhi * 8, SC);
  }

  bf16x8 ones;
#pragma unroll
  for (int j = 0; j < 8; j++) ones[j] = (__bf16)1.0f;

  const u16* kbase = qkv + rowb * QKVN + DIMN + h * HD;
  const u16* vbase = qkv + rowb * QKVN + 2 * DIMN + h * HD;
  const int sw = (llo & 7) * 8;
  const int rsw = llo & 7;

  const int srow = tid >> 3, su = tid & 7;
  const u16* ksrc = kbase + (size_t)srow * QKVN + (su ^ (srow & 7)) * 8;
  auto stageK = [&](int kt, int slot) {
    const u16* s0 = ksrc + (size_t)kt * 64 * QKVN;
    gload16(s0, (char*)&Ks[slot][0] + tid * 16);
    gload16(s0 + (size_t)32 * QKVN, (char*)&Ks[slot][0] + 4096 + tid * 16);
  };

  const int vp = (lane & 31) * 2;
  const int dc = w * 8 + (lane >> 5) * 32;
  auto loadV = [&](int kt, u16x8& a, u16x8& c) {
    const u16* vr = vbase + (size_t)(kt * 64 + vp) * QKVN + dc;
    a = *reinterpret_cast<const u16x8*>(vr);
    c = *reinterpret_cast<const u16x8*>(vr + QKVN);
  };
  auto writeV = [&](int buf, u16x8 a, u16x8 c) {
#pragma unroll
    for (int j = 0; j < 8; j++) {
      unsigned val = (unsigned)a[j] | ((unsigned)c[j] << 16);
      *reinterpret_cast<unsigned*>(&Vt[buf][(dc + j) * 64 + (vp ^ (j * 8))]) = val;
    }
  };

  u16x8 v0, v1, nv0, nv1;

  stageK(0, 0);
  loadV(0, v0, v1);
  stageK(1, 1);
  asm volatile("s_waitcnt vmcnt(2)" ::: "memory");
  writeV(0, v0, v1);
  asm volatile("s_waitcnt lgkmcnt(0)" ::: "memory");
  __builtin_amdgcn_s_barrier();
  __builtin_amdgcn_sched_barrier(0);

  f32x4 oacc[2][4] = {};
  f32x4 racc[2] = {};

  for (int t = 0; t < 16; t++) {
    if (t < 15) loadV(t + 1, nv0, nv1);

    const u16* kB = &Ks[t & 1][0];
    f32x4 sacc[4][2] = {};
#pragma unroll
    for (int ks = 0; ks < 2; ks++)
#pragma unroll
      for (int ni = 0; ni < 4; ni++) {
        bf16x8 kf = ld8(&kB[(ni * 16 + llo) * 64 + (((ks * 4 + lhi) ^ rsw) * 8)]);
#pragma unroll
        for (int mi = 0; mi < 2; mi++) sacc[ni][mi] = MFMA(kf, qb[mi][ks], sacc[ni][mi]);
      }

    asm volatile("s_waitcnt lgkmcnt(0)" ::: "memory");
    __builtin_amdgcn_s_barrier();  // all waves done reading Ks[t&1]
    __builtin_amdgcn_sched_barrier(0);
    if (t + 2 < 16) stageK(t + 2, t & 1);

#pragma unroll
    for (int mi = 0; mi < 2; mi++)
#pragma unroll
      for (int ni = 0; ni < 4; ni++) {
        float p0 = __builtin_amdgcn_exp2f(sacc[ni][mi][0]);
        float p1 = __builtin_amdgcn_exp2f(sacc[ni][mi][1]);
        float p2 = __builtin_amdgcn_exp2f(sacc[ni][mi][2]);
        float p3 = __builtin_amdgcn_exp2f(sacc[ni][mi][3]);
        u16* pp = &Ps[w][(mi * 16 + llo) * 64 + ((ni * 16 + lhi * 4) ^ sw)];
        uint2 pw;
        pw.x = pack_bf2(p0, p1);
        pw.y = pack_bf2(p2, p3);
        *reinterpret_cast<uint2*>(pp) = pw;  // ds_write_b64
      }

#pragma unroll
    for (int ks = 0; ks < 2; ks++) {
      const int koff = ks * 32 + lhi * 8;
      bf16x8 pa0 = ld8(&Ps[w][llo * 64 + (koff ^ sw)]);
      bf16x8 pa1 = ld8(&Ps[w][(16 + llo) * 64 + (koff ^ sw)]);
#pragma unroll
      for (int ni = 0; ni < 4; ni++) {
        bf16x8 vb = ld8(&Vt[t & 1][(ni * 16 + llo) * 64 + (koff ^ sw)]);
        oacc[0][ni] = MFMA(pa0, vb, oacc[0][ni]);
        oacc[1][ni] = MFMA(pa1, vb, oacc[1][ni]);
      }
      racc[0] = MFMA(pa0, ones, racc[0]);
      racc[1] = MFMA(pa1, ones, racc[1]);
    }

    if (t < 15) {
      if (t + 2 < 16) {
        asm volatile("s_waitcnt vmcnt(2)" ::: "memory");
      } else {
        asm volatile("s_waitcnt vmcnt(0)" ::: "memory");
      }
      writeV((t + 1) & 1, nv0, nv1);
      v0 = nv0; v1 = nv1;
      asm volatile("s_waitcnt lgkmcnt(0)" ::: "memory");
      __builtin_amdgcn_s_barrier();
      __builtin_amdgcn_sched_barrier(0);
    }
  }

#pragma unroll
  for (int mi = 0; mi < 2; mi++)
#pragma unroll
    for (int ni = 0; ni < 4; ni++)
#pragma unroll
      for (int r = 0; r < 4; r++) {
        const size_t row = rowb + wq0 + mi * 16 + lhi * 4 + r;
        outp[row * DIMN + h * HD + ni * 16 + llo] = f2bf(oacc[mi][ni][r] / racc[mi][r]);
      }
}

extern "C" void kernel_launch(void* const* d_in, const int* in_sizes, int n_in,
                              void* d_out, int out_size, void* d_ws, size_t ws_size,
                              hipStream_t stream) {
  const float* x = (const float*)d_in[0];
  const float* Wqkv = (const float*)d_in[1];
  const float* bqkv = (const float*)d_in[2];
  const float* Wproj = (const float*)d_in[3];
  const float* bproj = (const float*)d_in[4];
  const float* g1 = (const float*)d_in[5];
  const float* b1 = (const float*)d_in[6];
  const float* g2 = (const float*)d_in[7];
  const float* b2 = (const float*)d_in[8];
  const float* W1 = (const float*)d_in[9];
  const float* bf1 = (const float*)d_in[10];
  const float* W2 = (const float*)d_in[11];
  const float* bf2 = (const float*)d_in[12];
  float* outp = (float*)d_out;

  char* p = (char*)d_ws;
  u16* WqkvT = (u16*)p; p += (size_t)QKVN * DIMN * 2;
  u16* WprojT = (u16*)p; p += (size_t)DIMN * DIMN * 2;
  u16* W1T = (u16*)p; p += (size_t)HID * DIMN * 2;
  u16* W2T = (u16*)p; p += (size_t)DIMN * HID * 2;
  u16* bufX = (u16*)p; p += (size_t)BNROWS * DIMN * 2;  // h1 / attn_out / h2
  u16* big = (u16*)p; p += (size_t)BNROWS * HID * 2;    // qkv then ff1

  // fused pre-pass: 4 weight transposes + LN1 (one launch, 11008 blocks)
  pre_k<<<11008, 256, 0, stream>>>(Wqkv, Wproj, W1, W2, WqkvT, WprojT, W1T, W2T,
                                   x, g1, b1, bufX);

  // QKV GEMM -> big (bf16): 576 blocks, XCD-swizzled flat grid
  gemm256_k<1, 0, 0><<<64 * (QKVN / 256), 512, 0, stream>>>(bufX, WqkvT, bqkv, nullptr,
                                                            big, QKVN, DIMN);
  attn_k<<<1536, 256, 0, stream>>>(big, bufX);
  // proj GEMM + residual(x) -> d_out (fp32): 384 blocks
  gemmP_k<0, 0, 1><<<64 * (DIMN / 128), 256, 0, stream>>>(bufX, WprojT, bproj, x, outp,
                                                          DIMN, DIMN);
  ln_k<<<BNROWS / 4, 256, 0, stream>>>(outp, g2, b2, bufX);
  // FF1 (relu) -> big (bf16): 768 blocks
  gemm256_k<1, 1, 0><<<64 * (HID / 256), 512, 0, stream>>>(bufX, W1T, bf1, nullptr, big,
                                                           HID, DIMN);
  // FF2 + residual(d_out) -> d_out (fp32, in place): 384 blocks
  gemmP_k<0, 0, 1><<<64 * (DIMN / 128), 256, 0, stream>>>(big, W2T, bf2, outp, outp,
                                                          DIMN, HID);
}